// Round 1
// baseline (176.901 us; speedup 1.0000x reference)
//
#include <hip/hip_runtime.h>
#include <hip/hip_bf16.h>

#define NE 100
#define NB 4096
#define ND 256
#define NF 32
#define NH 16
#define NL 8
#define BT 256   // batch rows per block

__global__ __launch_bounds__(256)
void bagae_fused(const float* __restrict__ x,
                 const int* __restrict__ idx,
                 const float* __restrict__ We0, const float* __restrict__ be0,
                 const float* __restrict__ We1, const float* __restrict__ be1,
                 const float* __restrict__ Wl,  const float* __restrict__ bl,
                 const float* __restrict__ Wd0, const float* __restrict__ bd0,
                 const float* __restrict__ Wd1, const float* __restrict__ bd1,
                 const float* __restrict__ Wo,  const float* __restrict__ bo,
                 float* __restrict__ out)
{
    __shared__ float s_We0[NF * NH];
    __shared__ float s_We1[NH * NL];
    __shared__ float s_Wl [NL * NL];
    __shared__ float s_Wd0[NL * NH];
    __shared__ float s_Wd1[NH * NF];
    __shared__ float s_be0[NH], s_be1[NL], s_bl[NL], s_bd0[NH], s_bd1[NF];
    __shared__ int   s_idx[NF];
    __shared__ float s_d1[BT][36];   // stride 36 floats = 144 B (16B-aligned rows)

    const int tid = threadIdx.x;
    const int e   = blockIdx.y;
    const int b0  = blockIdx.x * BT;

    // ---- stage per-estimator small weights into LDS ----
    {
        const float* We0e = We0 + e * (NF * NH);
        const float* Wd1e = Wd1 + e * (NH * NF);
        for (int i = tid; i < NF * NH; i += 256) { s_We0[i] = We0e[i]; s_Wd1[i] = Wd1e[i]; }
        if (tid < NH * NL) { s_We1[tid] = We1[e * NH * NL + tid];
                             s_Wd0[tid] = Wd0[e * NL * NH + tid]; }
        if (tid < NL * NL) { s_Wl[tid]  = Wl [e * NL * NL + tid]; }
        if (tid < NF)      { s_idx[tid] = idx[e * NF + tid];
                             s_bd1[tid] = bd1[e * NF + tid]; }
        if (tid < NH)      { s_be0[tid] = be0[e * NH + tid];
                             s_bd0[tid] = bd0[e * NH + tid]; }
        if (tid < NL)      { s_be1[tid] = be1[e * NL + tid];
                             s_bl [tid] = bl [e * NL + tid]; }
    }
    __syncthreads();

    // ---- phase 1: each thread computes one batch row through the MLP chain ----
    {
        const float* xrow = x + (long)(b0 + tid) * ND;

        float xg[NF];
        #pragma unroll
        for (int f = 0; f < NF; ++f) xg[f] = xrow[s_idx[f]];

        float h0[NH];
        #pragma unroll
        for (int h = 0; h < NH; ++h) h0[h] = s_be0[h];
        #pragma unroll
        for (int f = 0; f < NF; ++f) {
            #pragma unroll
            for (int h = 0; h < NH; ++h)
                h0[h] = fmaf(xg[f], s_We0[f * NH + h], h0[h]);
        }
        // no ReLU on h0

        float h1[NL];
        #pragma unroll
        for (int l = 0; l < NL; ++l) h1[l] = s_be1[l];
        #pragma unroll
        for (int h = 0; h < NH; ++h) {
            #pragma unroll
            for (int l = 0; l < NL; ++l)
                h1[l] = fmaf(h0[h], s_We1[h * NL + l], h1[l]);
        }
        #pragma unroll
        for (int l = 0; l < NL; ++l) h1[l] = fmaxf(h1[l], 0.0f);

        float zz[NL];
        #pragma unroll
        for (int m = 0; m < NL; ++m) zz[m] = s_bl[m];
        #pragma unroll
        for (int l = 0; l < NL; ++l) {
            #pragma unroll
            for (int m = 0; m < NL; ++m)
                zz[m] = fmaf(h1[l], s_Wl[l * NL + m], zz[m]);
        }
        #pragma unroll
        for (int m = 0; m < NL; ++m) zz[m] = fmaxf(zz[m], 0.0f);

        float d0[NH];
        #pragma unroll
        for (int h = 0; h < NH; ++h) d0[h] = s_bd0[h];
        #pragma unroll
        for (int l = 0; l < NL; ++l) {
            #pragma unroll
            for (int h = 0; h < NH; ++h)
                d0[h] = fmaf(zz[l], s_Wd0[l * NH + h], d0[h]);
        }
        // no ReLU on d0

        float d1[NF];
        #pragma unroll
        for (int f = 0; f < NF; ++f) d1[f] = s_bd1[f];
        #pragma unroll
        for (int h = 0; h < NH; ++h) {
            #pragma unroll
            for (int f = 0; f < NF; ++f)
                d1[f] = fmaf(d0[h], s_Wd1[h * NF + f], d1[f]);
        }
        #pragma unroll
        for (int f = 0; f < NF; ++f)
            s_d1[tid][f] = fmaxf(d1[f], 0.0f);
    }
    __syncthreads();

    // ---- phase 2: thread t owns output column d = t for all BT rows ----
    {
        const int d = tid;
        const float* Woe = Wo + (long)e * NF * ND;

        float wo[NF];
        #pragma unroll
        for (int f = 0; f < NF; ++f) wo[f] = Woe[f * ND + d];   // coalesced across lanes
        const float bod = bo[e * ND + d];

        float* orow = out + ((long)e * NB + b0) * ND + d;
        for (int r = 0; r < BT; ++r) {
            const float* dr = s_d1[r];
            float acc = bod;
            #pragma unroll
            for (int f = 0; f < NF; ++f)
                acc = fmaf(dr[f], wo[f], acc);        // broadcast LDS reads
            float ex = __expf(-acc);
            float sg = __builtin_amdgcn_rcpf(1.0f + ex);
            __builtin_nontemporal_store(sg, orow + (long)r * ND);
        }
    }
}

extern "C" void kernel_launch(void* const* d_in, const int* in_sizes, int n_in,
                              void* d_out, int out_size, void* d_ws, size_t ws_size,
                              hipStream_t stream) {
    const float* x   = (const float*)d_in[0];
    const int*   idx = (const int*)  d_in[1];
    const float* We0 = (const float*)d_in[2];
    const float* be0 = (const float*)d_in[3];
    const float* We1 = (const float*)d_in[4];
    const float* be1 = (const float*)d_in[5];
    const float* Wl  = (const float*)d_in[6];
    const float* bl  = (const float*)d_in[7];
    const float* Wd0 = (const float*)d_in[8];
    const float* bd0 = (const float*)d_in[9];
    const float* Wd1 = (const float*)d_in[10];
    const float* bd1 = (const float*)d_in[11];
    const float* Wo  = (const float*)d_in[12];
    const float* bo  = (const float*)d_in[13];
    float* out = (float*)d_out;

    dim3 grid(NB / BT, NE);
    dim3 block(256);
    hipLaunchKernelGGL(bagae_fused, grid, block, 0, stream,
                       x, idx, We0, be0, We1, be1, Wl, bl,
                       Wd0, bd0, Wd1, bd1, Wo, bo, out);
}

// Round 5
// 151.656 us; speedup vs baseline: 1.1665x; 1.1665x over previous
//
#include <hip/hip_runtime.h>
#include <hip/hip_bf16.h>

#define NE 100
#define NB 4096
#define ND 256
#define NF 32
#define NH 16
#define NL 8
#define BT 256   // batch rows per block

typedef float f32x4 __attribute__((ext_vector_type(4)));

__device__ __forceinline__ float sigf(float a) {
    return __builtin_amdgcn_rcpf(1.0f + __expf(-a));
}

__global__ __launch_bounds__(256, 3)
void bagae_fused(const float* __restrict__ x,
                 const int* __restrict__ idx,
                 const float* __restrict__ We0, const float* __restrict__ be0,
                 const float* __restrict__ We1, const float* __restrict__ be1,
                 const float* __restrict__ Wl,  const float* __restrict__ bl,
                 const float* __restrict__ Wd0, const float* __restrict__ bd0,
                 const float* __restrict__ Wd1, const float* __restrict__ bd1,
                 const float* __restrict__ Wo,  const float* __restrict__ bo,
                 float* __restrict__ out)
{
    __shared__ float s_We0[NF * NH];
    __shared__ float s_We1[NH * NL];
    __shared__ float s_Wl [NL * NL];
    __shared__ float s_Wd0[NL * NH];
    __shared__ float s_Wd1[NH * NF];
    __shared__ float s_be0[NH], s_be1[NL], s_bl[NL], s_bd0[NH], s_bd1[NF];
    __shared__ int   s_idx[NF];
    __shared__ float s_d1[BT][36];   // stride 36 floats = 144 B (16B-aligned rows)

    const int tid = threadIdx.x;
    const int e   = blockIdx.y;
    const int b0  = blockIdx.x * BT;

    // ---- stage per-estimator small weights into LDS ----
    {
        const float* We0e = We0 + e * (NF * NH);
        const float* Wd1e = Wd1 + e * (NH * NF);
        for (int i = tid; i < NF * NH; i += 256) { s_We0[i] = We0e[i]; s_Wd1[i] = Wd1e[i]; }
        if (tid < NH * NL) { s_We1[tid] = We1[e * NH * NL + tid];
                             s_Wd0[tid] = Wd0[e * NL * NH + tid]; }
        if (tid < NL * NL) { s_Wl[tid]  = Wl [e * NL * NL + tid]; }
        if (tid < NF)      { s_idx[tid] = idx[e * NF + tid];
                             s_bd1[tid] = bd1[e * NF + tid]; }
        if (tid < NH)      { s_be0[tid] = be0[e * NH + tid];
                             s_bd0[tid] = bd0[e * NH + tid]; }
        if (tid < NL)      { s_be1[tid] = be1[e * NL + tid];
                             s_bl [tid] = bl [e * NL + tid]; }
    }
    __syncthreads();

    // ---- phase 1: each thread computes one batch row through the MLP chain ----
    {
        const float* xrow = x + (long)(b0 + tid) * ND;

        float xg[NF];
        #pragma unroll
        for (int f = 0; f < NF; ++f) xg[f] = xrow[s_idx[f]];

        float h0[NH];
        #pragma unroll
        for (int h = 0; h < NH; ++h) h0[h] = s_be0[h];
        #pragma unroll
        for (int f = 0; f < NF; ++f) {
            #pragma unroll
            for (int h = 0; h < NH; ++h)
                h0[h] = fmaf(xg[f], s_We0[f * NH + h], h0[h]);
        }
        // no ReLU on h0

        float h1[NL];
        #pragma unroll
        for (int l = 0; l < NL; ++l) h1[l] = s_be1[l];
        #pragma unroll
        for (int h = 0; h < NH; ++h) {
            #pragma unroll
            for (int l = 0; l < NL; ++l)
                h1[l] = fmaf(h0[h], s_We1[h * NL + l], h1[l]);
        }
        #pragma unroll
        for (int l = 0; l < NL; ++l) h1[l] = fmaxf(h1[l], 0.0f);

        float zz[NL];
        #pragma unroll
        for (int m = 0; m < NL; ++m) zz[m] = s_bl[m];
        #pragma unroll
        for (int l = 0; l < NL; ++l) {
            #pragma unroll
            for (int m = 0; m < NL; ++m)
                zz[m] = fmaf(h1[l], s_Wl[l * NL + m], zz[m]);
        }
        #pragma unroll
        for (int m = 0; m < NL; ++m) zz[m] = fmaxf(zz[m], 0.0f);

        float d0[NH];
        #pragma unroll
        for (int h = 0; h < NH; ++h) d0[h] = s_bd0[h];
        #pragma unroll
        for (int l = 0; l < NL; ++l) {
            #pragma unroll
            for (int h = 0; h < NH; ++h)
                d0[h] = fmaf(zz[l], s_Wd0[l * NH + h], d0[h]);
        }
        // no ReLU on d0

        float d1[NF];
        #pragma unroll
        for (int f = 0; f < NF; ++f) d1[f] = s_bd1[f];
        #pragma unroll
        for (int h = 0; h < NH; ++h) {
            #pragma unroll
            for (int f = 0; f < NF; ++f)
                d1[f] = fmaf(d0[h], s_Wd1[h * NF + f], d1[f]);
        }
        #pragma unroll
        for (int f = 0; f < NF; ++f)
            s_d1[tid][f] = fmaxf(d1[f], 0.0f);
    }
    __syncthreads();

    // ---- phase 2: register-tiled [BT x 32] @ [32 x 256] GEMM + sigmoid ----
    // Wave w owns rows [64w, 64w+64); lane l owns columns [4l, 4l+4).
    // Wo column-slab lives in 128 VGPRs; 8 broadcast ds_read_b128 per row
    // feed 256 outputs (vs 64 before) -> LDS pipe pressure / 4.
    {
        const int w  = tid >> 6;      // wave id
        const int l  = tid & 63;      // lane
        const int c0 = l * 4;         // column base (coalesced float4 across wave)
        const float* Woe = Wo + (long)e * NF * ND;

        f32x4 wo4[NF];
        #pragma unroll
        for (int k = 0; k < NF; ++k)
            wo4[k] = *reinterpret_cast<const f32x4*>(Woe + k * ND + c0);  // coalesced dwordx4
        const f32x4 bo4 = *reinterpret_cast<const f32x4*>(bo + e * ND + c0);

        const int r0 = w * 64;
        float* obase = out + ((long)e * NB + b0 + r0) * ND + c0;

        for (int r = 0; r < 64; ++r) {
            const f32x4* dr4 = reinterpret_cast<const f32x4*>(s_d1[r0 + r]);
            float a0 = bo4.x, a1 = bo4.y, a2 = bo4.z, a3 = bo4.w;
            #pragma unroll
            for (int q = 0; q < 8; ++q) {
                f32x4 dv = dr4[q];                 // broadcast ds_read_b128
                a0 = fmaf(dv.x, wo4[4*q+0].x, a0);
                a1 = fmaf(dv.x, wo4[4*q+0].y, a1);
                a2 = fmaf(dv.x, wo4[4*q+0].z, a2);
                a3 = fmaf(dv.x, wo4[4*q+0].w, a3);
                a0 = fmaf(dv.y, wo4[4*q+1].x, a0);
                a1 = fmaf(dv.y, wo4[4*q+1].y, a1);
                a2 = fmaf(dv.y, wo4[4*q+1].z, a2);
                a3 = fmaf(dv.y, wo4[4*q+1].w, a3);
                a0 = fmaf(dv.z, wo4[4*q+2].x, a0);
                a1 = fmaf(dv.z, wo4[4*q+2].y, a1);
                a2 = fmaf(dv.z, wo4[4*q+2].z, a2);
                a3 = fmaf(dv.z, wo4[4*q+2].w, a3);
                a0 = fmaf(dv.w, wo4[4*q+3].x, a0);
                a1 = fmaf(dv.w, wo4[4*q+3].y, a1);
                a2 = fmaf(dv.w, wo4[4*q+3].z, a2);
                a3 = fmaf(dv.w, wo4[4*q+3].w, a3);
            }
            f32x4 o;
            o.x = sigf(a0);
            o.y = sigf(a1);
            o.z = sigf(a2);
            o.w = sigf(a3);
            __builtin_nontemporal_store(o, reinterpret_cast<f32x4*>(obase + (long)r * ND));
        }
    }
}

extern "C" void kernel_launch(void* const* d_in, const int* in_sizes, int n_in,
                              void* d_out, int out_size, void* d_ws, size_t ws_size,
                              hipStream_t stream) {
    const float* x   = (const float*)d_in[0];
    const int*   idx = (const int*)  d_in[1];
    const float* We0 = (const float*)d_in[2];
    const float* be0 = (const float*)d_in[3];
    const float* We1 = (const float*)d_in[4];
    const float* be1 = (const float*)d_in[5];
    const float* Wl  = (const float*)d_in[6];
    const float* bl  = (const float*)d_in[7];
    const float* Wd0 = (const float*)d_in[8];
    const float* bd0 = (const float*)d_in[9];
    const float* Wd1 = (const float*)d_in[10];
    const float* bd1 = (const float*)d_in[11];
    const float* Wo  = (const float*)d_in[12];
    const float* bo  = (const float*)d_in[13];
    float* out = (float*)d_out;

    dim3 grid(NB / BT, NE);
    dim3 block(256);
    hipLaunchKernelGGL(bagae_fused, grid, block, 0, stream,
                       x, idx, We0, be0, We1, be1, Wl, bl,
                       Wd0, bd0, Wd1, bd1, Wo, bo, out);
}